// Round 6
// baseline (1156.055 us; speedup 1.0000x reference)
//
#include <hip/hip_runtime.h>
#include <hip/hip_bf16.h>

// MoE expert MLP: y[b] = (gelu(x[b] @ W1[e] + b1[e]) @ W2[e] + b2[e]) * w[b]
// B=8, S=4096, D=1024, F=4096, E=8. f32 in/out; bf16 MFMA 32x32x16, 256^2 tile.

#define B_ 8
#define S_ 4096
#define D_ 1024
#define F_ 4096
#define E_ 8

typedef __bf16 bf16x8 __attribute__((ext_vector_type(8)));
typedef float f32x16 __attribute__((ext_vector_type(16)));

__device__ __forceinline__ unsigned short f2bf(float f) {
  unsigned u = __float_as_uint(f);
  u += 0x7FFFu + ((u >> 16) & 1u);   // round-to-nearest-even
  return (unsigned short)(u >> 16);
}

#define GLD16(g, l) __builtin_amdgcn_global_load_lds(                         \
    (const __attribute__((address_space(1))) unsigned int*)(g),              \
    (__attribute__((address_space(3))) unsigned int*)(l), 16, 0, 0)

// ---------------------------------------------------------------------------
// Transpose + f32->bf16:  src (nmat, R, C) f32  ->  dst (nmat, C, R) bf16
// ---------------------------------------------------------------------------
__global__ __launch_bounds__(256) void transpose_cvt_kernel(
    const float* __restrict__ src, unsigned short* __restrict__ dst,
    int R, int C) {
  __shared__ float t[32][33];
  const float* s = src + (size_t)blockIdx.z * R * C;
  unsigned short* d = dst + (size_t)blockIdx.z * R * C;
  int c0 = blockIdx.x * 32, r0 = blockIdx.y * 32;
  int x = threadIdx.x, y = threadIdx.y;      // 32 x 8
#pragma unroll
  for (int j = 0; j < 32; j += 8)
    t[y + j][x] = s[(size_t)(r0 + y + j) * C + (c0 + x)];
  __syncthreads();
#pragma unroll
  for (int j = 0; j < 32; j += 8)
    d[(size_t)(c0 + y + j) * R + (r0 + x)] = f2bf(t[x][y + j]);
}

// ---------------------------------------------------------------------------
// f32 -> bf16 flat convert, vectorized
// ---------------------------------------------------------------------------
__global__ __launch_bounds__(256) void cvt_bf16_kernel(
    const float* __restrict__ src, unsigned short* __restrict__ dst, long n4) {
  long i = (long)blockIdx.x * 256 + threadIdx.x;
  long stride = (long)gridDim.x * 256;
  for (; i < n4; i += stride) {
    float4 v = ((const float4*)src)[i];
    uint2 o;
    o.x = (unsigned)f2bf(v.x) | ((unsigned)f2bf(v.y) << 16);
    o.y = (unsigned)f2bf(v.z) | ((unsigned)f2bf(v.w) << 16);
    ((uint2*)dst)[i] = o;
  }
}

// ---------------------------------------------------------------------------
// 256x256-tile 4-phase GEMM with mfma_f32_32x32x16_bf16 (R6).
//   8 waves (2M x 4N); per-wave output 128x64 = 4 m-tiles(32) x 2 n-tiles(32)
//   (rows split across the two A halves; cols split across the two B halves).
//   BK=64 -> 4 k-steps of 16 per tile; 32 MFMA/wave/tile (was 64 at 16x16).
//   LDS 128 KiB: buf{0,1} x { A[2 halves 128x64] , B[2 halves 128x64] },
//   16B-chunk XOR swizzle: chunk cc of row r holds global k-chunk cc^(r&7).
//   Frag layouts (guide-verified m74/m101 family):
//     A: row=l&31, k=(l>>5)*8+j   B: col=l&31, k=(l>>5)*8+j
//     C/D: col=l&31, row=(reg&3)+8*(reg>>2)+4*(l>>5)
//   Staging issue order per tile t: ph1 Ah1(t+1), ph2 Ah0(t+2), ph3 Bh0(t+2),
//   ph4 Bh1(t+2); vmcnt(6) only at ph4 (3 half-tiles in flight).
// ---------------------------------------------------------------------------

#define STAGE(cur, op, h, tk, base)                                           \
  {                                                                           \
    const unsigned short* g0_ = (base) + (size_t)((h) * 128 + sr) * LDK +     \
                                (tk) * 64 + sgc * 8;                          \
    GLD16(g0_, smem + (cur) * 65536 + (op) * 32768 + (h) * 16384 +            \
                   wave * 1024);                                              \
    GLD16(g0_ + (size_t)64 * LDK,                                             \
          smem + (cur) * 65536 + (op) * 32768 + (h) * 16384 + 8192 +          \
              wave * 1024);                                                   \
  }

#define LDA32(cur, H)                                                         \
  _Pragma("unroll") for (int ks = 0; ks < 4; ++ks) {                          \
    const char* pa_ = smem + (cur) * 65536 + (H) * 16384;                     \
    aH[0][ks] = *(const bf16x8*)(pa_ + rA0 + cofs[ks]);                       \
    aH[1][ks] = *(const bf16x8*)(pa_ + rA1 + cofs[ks]);                       \
  }

#define LDB32(cur, Q, breg)                                                   \
  _Pragma("unroll") for (int ks = 0; ks < 4; ++ks)                            \
      breg[ks] = *(const bf16x8*)(smem + (cur) * 65536 + 32768 +              \
                                  (Q) * 16384 + rB0 + cofs[ks]);

#define MMA32(HH, Q, breg)                                                    \
  _Pragma("unroll") for (int ks = 0; ks < 4; ++ks) {                          \
    acc[(HH) * 2 + 0][Q] = __builtin_amdgcn_mfma_f32_32x32x16_bf16(           \
        aH[0][ks], breg[ks], acc[(HH) * 2 + 0][Q], 0, 0, 0);                  \
    acc[(HH) * 2 + 1][Q] = __builtin_amdgcn_mfma_f32_32x32x16_bf16(           \
        aH[1][ks], breg[ks], acc[(HH) * 2 + 1][Q], 0, 0, 0);                  \
  }

#define PH_END                                                                \
  __builtin_amdgcn_s_setprio(0);                                              \
  __builtin_amdgcn_sched_barrier(0);                                          \
  __builtin_amdgcn_s_barrier();

// MODE: 2 = full staging, 1 = tail-1 (stage Ah1 only, drain), 0 = last tile
#define TILE(cur, t, MODE)                                                    \
  LDA32(cur, 0);                                                              \
  LDB32(cur, 0, bq0);                                                         \
  if ((MODE) >= 1) STAGE((cur) ^ 1, 0, 1, (t) + 1, Abase);                    \
  __builtin_amdgcn_s_setprio(1);                                              \
  MMA32(0, 0, bq0);                                                           \
  PH_END;                                                                     \
  LDB32(cur, 1, bq1);                                                         \
  if ((MODE) == 2) STAGE(cur, 0, 0, (t) + 2, Abase);                          \
  __builtin_amdgcn_s_setprio(1);                                              \
  MMA32(0, 1, bq1);                                                           \
  PH_END;                                                                     \
  LDA32(cur, 1);                                                              \
  if ((MODE) == 2) STAGE(cur, 1, 0, (t) + 2, Bbase);                          \
  __builtin_amdgcn_s_setprio(1);                                              \
  MMA32(1, 0, bq0);                                                           \
  PH_END;                                                                     \
  if ((MODE) == 2) STAGE(cur, 1, 1, (t) + 2, Bbase);                          \
  __builtin_amdgcn_s_setprio(1);                                              \
  MMA32(1, 1, bq1);                                                           \
  __builtin_amdgcn_s_setprio(0);                                              \
  __builtin_amdgcn_sched_barrier(0);                                          \
  if ((MODE) == 2) asm volatile("s_waitcnt vmcnt(6)" ::: "memory");           \
  if ((MODE) == 1) asm volatile("s_waitcnt vmcnt(0)" ::: "memory");           \
  __builtin_amdgcn_s_barrier();

template <int NT, int LDK, int NCOL, bool GELU>
__global__ __launch_bounds__(512, 2) void gemm8p_kernel(
    const unsigned short* __restrict__ A,   // [rows][LDK] bf16 (chunk-local)
    const unsigned short* __restrict__ Bw,  // [E][NCOL][LDK] bf16
    const float* __restrict__ bias,         // [E][NCOL]
    const int* __restrict__ eidx, const float* __restrict__ ew,
    void* __restrict__ Out, int grow0, int nbm) {
  extern __shared__ __align__(16) char smem[];

  const int tid = threadIdx.x;
  const int lane = tid & 63;
  const int wave = tid >> 6;
  const int wr = wave >> 2;         // 0..1 (M)
  const int wc = wave & 3;          // 0..3 (N)
  const int l31 = lane & 31;
  const int g5 = lane >> 5;
  const int l7 = lane & 7;

  const int nwg = nbm * (NCOL / 256);
  int wg = blockIdx.x;
  if ((nwg & 7) == 0) wg = (wg & 7) * (nwg >> 3) + (wg >> 3);  // XCD swizzle
  const int bm = wg % nbm, bn = wg / nbm;

  const int bat = (grow0 + bm * 256) >> 12;
  const int e = eidx[bat];

  const unsigned short* Abase = A + (size_t)bm * 256 * LDK;
  const unsigned short* Bbase =
      Bw + (size_t)e * (F_ * D_) + (size_t)bn * 256 * LDK;

  // staging per-thread constants (swizzled source)
  const int sr = tid >> 3;                  // 0..63 (row within 64-row slab)
  const int sgc = (tid & 7) ^ (sr & 7);     // global 16B chunk for lds chunk
  // ds_read per-thread constants (row&7 == l7 for all tile rows)
  const int rA0 = (wr * 64 + l31) * 128;    // A half-local row byte offset
  const int rA1 = rA0 + 32 * 128;
  const int rB0 = (wc * 32 + l31) * 128;    // B half-local row byte offset
  int cofs[4];
#pragma unroll
  for (int ks = 0; ks < 4; ++ks) cofs[ks] = (((ks * 2 + g5) ^ l7) << 4);

  f32x16 acc[4][2] = {};                    // [m-tile 0..3][B-half]
  bf16x8 aH[2][4], bq0[4], bq1[4];

  // prologue: tile0 all 4 halves, tile1 first 3 (Ah0,Bh0,Bh1)
  STAGE(0, 0, 0, 0, Abase);
  STAGE(0, 1, 0, 0, Bbase);
  STAGE(0, 1, 1, 0, Bbase);
  STAGE(0, 0, 1, 0, Abase);
  STAGE(1, 0, 0, 1, Abase);
  STAGE(1, 1, 0, 1, Bbase);
  STAGE(1, 1, 1, 1, Bbase);
  asm volatile("s_waitcnt vmcnt(6)" ::: "memory");
  __builtin_amdgcn_s_barrier();

#pragma unroll 1
  for (int t = 0; t < NT - 2; t += 2) {
    TILE(0, t, 2);
    TILE(1, t + 1, 2);
  }
  TILE(0, NT - 2, 1);
  TILE(1, NT - 1, 0);

  // epilogue: C/D map col=l&31, row=(reg&3)+8*(reg>>2)+4*(l>>5)
  const float scale = GELU ? 1.0f : ew[bat];
#pragma unroll
  for (int q = 0; q < 2; ++q) {
    const int col = bn * 256 + q * 128 + wc * 32 + l31;
    const float bv = bias[(size_t)e * NCOL + col];
#pragma unroll
    for (int mtg = 0; mtg < 4; ++mtg) {
      const int rb = bm * 256 +
                     (mtg < 2 ? wr * 64 + mtg * 32
                              : 128 + wr * 64 + (mtg - 2) * 32) +
                     4 * g5;
#pragma unroll
      for (int rg = 0; rg < 16; ++rg) {
        const size_t row = rb + (rg & 3) + 8 * (rg >> 2);
        float v = acc[mtg][q][rg] + bv;
        if (GELU) {
          // tanh-form gelu: v * sigmoid(2 * 0.79788456*(v + 0.044715 v^3))
          float zz = v * (0.79788456080286536f + 0.0356774081f * v * v);
          float g = v / (1.0f + __expf(-2.0f * zz));
          ((unsigned short*)Out)[row * NCOL + col] = f2bf(g);
        } else {
          ((float*)Out)[row * NCOL + col] = v * scale;
        }
      }
    }
  }
}

// ---------------------------------------------------------------------------
extern "C" void kernel_launch(void* const* d_in, const int* in_sizes, int n_in,
                              void* d_out, int out_size, void* d_ws,
                              size_t ws_size, hipStream_t stream) {
  const float* x = (const float*)d_in[0];
  const float* ew = (const float*)d_in[1];
  const float* W1 = (const float*)d_in[2];
  const float* b1 = (const float*)d_in[3];
  const float* W2 = (const float*)d_in[4];
  const float* b2 = (const float*)d_in[5];
  const int* eidx = (const int*)d_in[6];
  float* out = (float*)d_out;

  char* ws = (char*)d_ws;
  const size_t WT = (size_t)E_ * F_ * D_ * 2;  // 64 MiB per transposed weight
  const size_t XB = (size_t)B_ * S_ * D_ * 2;  // 64 MiB bf16 x
  unsigned short* w1t = (unsigned short*)ws;
  unsigned short* w2t = (unsigned short*)(ws + WT);

  auto g1 = gemm8p_kernel<16, D_, F_, true>;
  auto g2 = gemm8p_kernel<64, F_, D_, false>;
  hipFuncSetAttribute((const void*)g1,
                      hipFuncAttributeMaxDynamicSharedMemorySize, 131072);
  hipFuncSetAttribute((const void*)g2,
                      hipFuncAttributeMaxDynamicSharedMemorySize, 131072);

  // weights: W1 (E,D,F)->(E,F,D), W2 (E,F,D)->(E,D,F), bf16
  transpose_cvt_kernel<<<dim3(F_ / 32, D_ / 32, E_), dim3(32, 8), 0, stream>>>(
      W1, w1t, D_, F_);
  transpose_cvt_kernel<<<dim3(D_ / 32, F_ / 32, E_), dim3(32, 8), 0, stream>>>(
      W2, w2t, F_, D_);

  const long total_rows = (long)B_ * S_;  // 32768
  long hcap = ((long)ws_size - (long)(2 * WT + XB)) / ((long)F_ * 2);

  if (hcap >= total_rows) {
    // full: [w1t][w2t][xbf][hbuf]
    unsigned short* xbf = (unsigned short*)(ws + 2 * WT);
    unsigned short* hbuf = (unsigned short*)(ws + 2 * WT + XB);
    cvt_bf16_kernel<<<2048, 256, 0, stream>>>(x, xbf, (long)B_ * S_ * D_ / 4);
    int nbm = (int)(total_rows / 256);
    g1<<<dim3(nbm * (F_ / 256)), 512, 131072, stream>>>(
        xbf, w1t, b1, eidx, ew, hbuf, 0, nbm);
    g2<<<dim3(nbm * (D_ / 256)), 512, 131072, stream>>>(
        hbuf, w2t, b2, eidx, ew, out, 0, nbm);
  } else {
    // chunked: [w1t][w2t][xbf_chunk][h_chunk]
    long cap = ((long)ws_size - (long)(2 * WT)) / ((long)(D_ + F_) * 2);
    long chunk = (cap / 256) * 256;
    if (chunk > total_rows) chunk = total_rows;
    if (chunk < 256) chunk = 256;
    unsigned short* xbf = (unsigned short*)(ws + 2 * WT);
    unsigned short* hbuf = xbf + (size_t)chunk * D_;
    for (long r0 = 0; r0 < total_rows; r0 += chunk) {
      long nr = total_rows - r0;
      if (nr > chunk) nr = chunk;
      cvt_bf16_kernel<<<512, 256, 0, stream>>>(x + r0 * D_, xbf, nr * D_ / 4);
      int nbm = (int)(nr / 256);
      g1<<<dim3(nbm * (F_ / 256)), 512, 131072, stream>>>(
          xbf, w1t, b1, eidx, ew, hbuf, (int)r0, nbm);
      g2<<<dim3(nbm * (D_ / 256)), 512, 131072, stream>>>(
          hbuf, w2t, b2, eidx, ew, out + r0 * D_, (int)r0, nbm);
    }
  }
}

// Round 7
// 824.478 us; speedup vs baseline: 1.4022x; 1.4022x over previous
//
#include <hip/hip_runtime.h>
#include <hip/hip_bf16.h>

// MoE expert MLP: y[b] = (gelu(x[b] @ W1[e] + b1[e]) @ W2[e] + b2[e]) * w[b]
// B=8, S=4096, D=1024, F=4096, E=8. f32 in/out; bf16 MFMA 16x16x32, 256^2 tile.

#define B_ 8
#define S_ 4096
#define D_ 1024
#define F_ 4096
#define E_ 8

typedef __bf16 bf16x8 __attribute__((ext_vector_type(8)));
typedef float f32x4 __attribute__((ext_vector_type(4)));

__device__ __forceinline__ unsigned short f2bf(float f) {
  unsigned u = __float_as_uint(f);
  u += 0x7FFFu + ((u >> 16) & 1u);   // round-to-nearest-even
  return (unsigned short)(u >> 16);
}

#define GLD16(g, l) __builtin_amdgcn_global_load_lds(                         \
    (const __attribute__((address_space(1))) unsigned int*)(g),              \
    (__attribute__((address_space(3))) unsigned int*)(l), 16, 0, 0)

// ---------------------------------------------------------------------------
// Transpose + f32->bf16:  src (nmat, R, C) f32  ->  dst (nmat, C, R) bf16
// ---------------------------------------------------------------------------
__global__ __launch_bounds__(256) void transpose_cvt_kernel(
    const float* __restrict__ src, unsigned short* __restrict__ dst,
    int R, int C) {
  __shared__ float t[32][33];
  const float* s = src + (size_t)blockIdx.z * R * C;
  unsigned short* d = dst + (size_t)blockIdx.z * R * C;
  int c0 = blockIdx.x * 32, r0 = blockIdx.y * 32;
  int x = threadIdx.x, y = threadIdx.y;      // 32 x 8
#pragma unroll
  for (int j = 0; j < 32; j += 8)
    t[y + j][x] = s[(size_t)(r0 + y + j) * C + (c0 + x)];
  __syncthreads();
#pragma unroll
  for (int j = 0; j < 32; j += 8)
    d[(size_t)(c0 + y + j) * R + (r0 + x)] = f2bf(t[x][y + j]);
}

// ---------------------------------------------------------------------------
// f32 -> bf16 flat convert, vectorized
// ---------------------------------------------------------------------------
__global__ __launch_bounds__(256) void cvt_bf16_kernel(
    const float* __restrict__ src, unsigned short* __restrict__ dst, long n4) {
  long i = (long)blockIdx.x * 256 + threadIdx.x;
  long stride = (long)gridDim.x * 256;
  for (; i < n4; i += stride) {
    float4 v = ((const float4*)src)[i];
    uint2 o;
    o.x = (unsigned)f2bf(v.x) | ((unsigned)f2bf(v.y) << 16);
    o.y = (unsigned)f2bf(v.z) | ((unsigned)f2bf(v.w) << 16);
    ((uint2*)dst)[i] = o;
  }
}

// ---------------------------------------------------------------------------
// 256x256-tile GEMM, ONE phase / ONE barrier per K-tile (R7, T3-minimum).
//   8 waves (2M x 4N), per-wave 128x64 output, BK=64, mfma 16x16x32 bf16.
//   LDS 128 KiB: buf{0,1} x { A[2 halves 128x64] , B[2 halves 128x64] },
//   16B-chunk XOR swizzle: chunk cc of row r holds global k-chunk cc^(r&7)
//   (verified 0 bank conflicts for the 16x16 read pattern, R5).
//   Tile body: issue 8 global_load_lds (t+1 -> buf^1) FIRST, then 24
//   ds_read_b128 + 64 MFMA with NO fences (no setprio/sched_barrier) so the
//   compiler's counted lgkmcnt interleaves ds_read drain with MFMA; then
//   vmcnt(0) (loads issued a full tile earlier -> ~free) + one s_barrier.
//   Safety: stages target buf^1 only (disjoint from all reads of buf);
//   each wave's reads complete before its barrier (MFMA consumed them), so
//   next tile's stages into buf cannot race any wave's reads.
// ---------------------------------------------------------------------------

#define STAGE(cur, op, h, tk, base)                                           \
  {                                                                           \
    const unsigned short* g0_ = (base) + (size_t)((h) * 128 + sr) * LDK +     \
                                (tk) * 64 + sgc * 8;                          \
    GLD16(g0_, smem + (cur) * 65536 + (op) * 32768 + (h) * 16384 +            \
                   wave * 1024);                                              \
    GLD16(g0_ + (size_t)64 * LDK,                                             \
          smem + (cur) * 65536 + (op) * 32768 + (h) * 16384 + 8192 +          \
              wave * 1024);                                                   \
  }

#define LDA_HALF(cur, H)                                                      \
  _Pragma("unroll") for (int m = 0; m < 4; ++m) {                             \
    const char* p_ = smem + (cur) * 65536 + (H) * 16384 +                     \
                     (wr * 64 + m * 16 + l15) * 128;                          \
    aM[m][0] = *(const bf16x8*)(p_ + ca0);                                    \
    aM[m][1] = *(const bf16x8*)(p_ + ca1);                                    \
  }

#define LDB_Q(cur, Q, breg)                                                   \
  _Pragma("unroll") for (int n = 0; n < 2; ++n) {                             \
    const char* p_ = smem + (cur) * 65536 + 32768 + (Q) * 16384 +             \
                     (wc * 32 + n * 16 + l15) * 128;                          \
    breg[n][0] = *(const bf16x8*)(p_ + ca0);                                  \
    breg[n][1] = *(const bf16x8*)(p_ + ca1);                                  \
  }

#define MMA_Q(MB, breg, NB)                                                   \
  _Pragma("unroll") for (int ks = 0; ks < 2; ++ks)                            \
      _Pragma("unroll") for (int m = 0; m < 4; ++m)                           \
          _Pragma("unroll") for (int n = 0; n < 2; ++n)                       \
              acc[(MB) + m][(NB) + n] =                                       \
      __builtin_amdgcn_mfma_f32_16x16x32_bf16(                                \
          aM[m][ks], breg[n][ks], acc[(MB) + m][(NB) + n], 0, 0, 0);

// MODE: 1 = stage tile t+1 into buf^1, 0 = last tile (no staging)
#define TILE(cur, t, MODE)                                                    \
  if ((MODE) >= 1) {                                                          \
    STAGE((cur) ^ 1, 0, 0, (t) + 1, Abase);                                   \
    STAGE((cur) ^ 1, 1, 0, (t) + 1, Bbase);                                   \
    STAGE((cur) ^ 1, 0, 1, (t) + 1, Abase);                                   \
    STAGE((cur) ^ 1, 1, 1, (t) + 1, Bbase);                                   \
  }                                                                           \
  LDA_HALF(cur, 0);                                                           \
  LDB_Q(cur, 0, bq0);                                                         \
  LDB_Q(cur, 1, bq1);                                                         \
  MMA_Q(0, bq0, 0);                                                           \
  MMA_Q(0, bq1, 2);                                                           \
  LDA_HALF(cur, 1);                                                           \
  MMA_Q(4, bq0, 0);                                                           \
  MMA_Q(4, bq1, 2);                                                           \
  if ((MODE) >= 1) {                                                          \
    asm volatile("s_waitcnt vmcnt(0)" ::: "memory");                          \
    __builtin_amdgcn_s_barrier();                                             \
  }

template <int NT, int LDK, int NCOL, bool GELU>
__global__ __launch_bounds__(512, 2) void gemm8p_kernel(
    const unsigned short* __restrict__ A,   // [rows][LDK] bf16 (chunk-local)
    const unsigned short* __restrict__ Bw,  // [E][NCOL][LDK] bf16
    const float* __restrict__ bias,         // [E][NCOL]
    const int* __restrict__ eidx, const float* __restrict__ ew,
    void* __restrict__ Out, int grow0, int nbm) {
  extern __shared__ __align__(16) char smem[];

  const int tid = threadIdx.x;
  const int lane = tid & 63;
  const int wave = tid >> 6;
  const int wr = wave >> 2;         // 0..1 (M)
  const int wc = wave & 3;          // 0..3 (N)
  const int l15 = lane & 15, lhi = lane >> 4;

  const int nwg = nbm * (NCOL / 256);
  int wg = blockIdx.x;
  if ((nwg & 7) == 0) wg = (wg & 7) * (nwg >> 3) + (wg >> 3);  // XCD swizzle
  const int bm = wg % nbm, bn = wg / nbm;

  const int bat = (grow0 + bm * 256) >> 12;
  const int e = eidx[bat];

  const unsigned short* Abase = A + (size_t)bm * 256 * LDK;
  const unsigned short* Bbase =
      Bw + (size_t)e * (F_ * D_) + (size_t)bn * 256 * LDK;

  // staging per-thread constants (swizzled source)
  const int sr = tid >> 3;                  // 0..63 (row within 64-row slab)
  const int sgc = (tid & 7) ^ (sr & 7);     // global 16B chunk for lds chunk
  // ds_read per-thread swizzled chunk offsets (row&7 == l15&7 always)
  const int ca0 = ((lhi ^ (l15 & 7)) << 4);
  const int ca1 = (((4 + lhi) ^ (l15 & 7)) << 4);

  f32x4 acc[8][4] = {};
  bf16x8 aM[4][2], bq0[2][2], bq1[2][2];

  // prologue: stage tile0 into buf0, cold drain (once)
  STAGE(0, 0, 0, 0, Abase);
  STAGE(0, 1, 0, 0, Bbase);
  STAGE(0, 0, 1, 0, Abase);
  STAGE(0, 1, 1, 0, Bbase);
  asm volatile("s_waitcnt vmcnt(0)" ::: "memory");
  __builtin_amdgcn_s_barrier();

#pragma unroll 1
  for (int t = 0; t < NT - 2; t += 2) {
    TILE(0, t, 1);
    TILE(1, t + 1, 1);
  }
  TILE(0, NT - 2, 1);
  TILE(1, NT - 1, 0);

  // epilogue
  const float scale = GELU ? 1.0f : ew[bat];
#pragma unroll
  for (int n = 0; n < 4; ++n) {
    const int tcol =
        (n < 2 ? wc * 32 + n * 16 : 128 + wc * 32 + (n - 2) * 16) + l15;
    const int col = bn * 256 + tcol;
    const float bv = bias[(size_t)e * NCOL + col];
#pragma unroll
    for (int m = 0; m < 8; ++m) {
      const int trow =
          (m < 4 ? wr * 64 + m * 16 : 128 + wr * 64 + (m - 4) * 16) + lhi * 4;
      const size_t rowb = (size_t)bm * 256 + trow;
#pragma unroll
      for (int r = 0; r < 4; ++r) {
        float v = acc[m][n][r] + bv;
        if (GELU) {
          // tanh-form gelu: v * sigmoid(2 * 0.79788456*(v + 0.044715 v^3))
          float zz = v * (0.79788456080286536f + 0.0356774081f * v * v);
          float g = v / (1.0f + __expf(-2.0f * zz));
          ((unsigned short*)Out)[(rowb + r) * NCOL + col] = f2bf(g);
        } else {
          ((float*)Out)[(rowb + r) * NCOL + col] = v * scale;
        }
      }
    }
  }
}

// ---------------------------------------------------------------------------
extern "C" void kernel_launch(void* const* d_in, const int* in_sizes, int n_in,
                              void* d_out, int out_size, void* d_ws,
                              size_t ws_size, hipStream_t stream) {
  const float* x = (const float*)d_in[0];
  const float* ew = (const float*)d_in[1];
  const float* W1 = (const float*)d_in[2];
  const float* b1 = (const float*)d_in[3];
  const float* W2 = (const float*)d_in[4];
  const float* b2 = (const float*)d_in[5];
  const int* eidx = (const int*)d_in[6];
  float* out = (float*)d_out;

  char* ws = (char*)d_ws;
  const size_t WT = (size_t)E_ * F_ * D_ * 2;  // 64 MiB per transposed weight
  const size_t XB = (size_t)B_ * S_ * D_ * 2;  // 64 MiB bf16 x
  unsigned short* w1t = (unsigned short*)ws;
  unsigned short* w2t = (unsigned short*)(ws + WT);

  auto g1 = gemm8p_kernel<16, D_, F_, true>;
  auto g2 = gemm8p_kernel<64, F_, D_, false>;
  hipFuncSetAttribute((const void*)g1,
                      hipFuncAttributeMaxDynamicSharedMemorySize, 131072);
  hipFuncSetAttribute((const void*)g2,
                      hipFuncAttributeMaxDynamicSharedMemorySize, 131072);

  // weights: W1 (E,D,F)->(E,F,D), W2 (E,F,D)->(E,D,F), bf16
  transpose_cvt_kernel<<<dim3(F_ / 32, D_ / 32, E_), dim3(32, 8), 0, stream>>>(
      W1, w1t, D_, F_);
  transpose_cvt_kernel<<<dim3(D_ / 32, F_ / 32, E_), dim3(32, 8), 0, stream>>>(
      W2, w2t, F_, D_);

  const long total_rows = (long)B_ * S_;  // 32768
  long hcap = ((long)ws_size - (long)(2 * WT + XB)) / ((long)F_ * 2);

  if (hcap >= total_rows) {
    // full: [w1t][w2t][xbf][hbuf]
    unsigned short* xbf = (unsigned short*)(ws + 2 * WT);
    unsigned short* hbuf = (unsigned short*)(ws + 2 * WT + XB);
    cvt_bf16_kernel<<<2048, 256, 0, stream>>>(x, xbf, (long)B_ * S_ * D_ / 4);
    int nbm = (int)(total_rows / 256);
    g1<<<dim3(nbm * (F_ / 256)), 512, 131072, stream>>>(
        xbf, w1t, b1, eidx, ew, hbuf, 0, nbm);
    g2<<<dim3(nbm * (D_ / 256)), 512, 131072, stream>>>(
        hbuf, w2t, b2, eidx, ew, out, 0, nbm);
  } else {
    // chunked: [w1t][w2t][xbf_chunk][h_chunk]
    long cap = ((long)ws_size - (long)(2 * WT)) / ((long)(D_ + F_) * 2);
    long chunk = (cap / 256) * 256;
    if (chunk > total_rows) chunk = total_rows;
    if (chunk < 256) chunk = 256;
    unsigned short* xbf = (unsigned short*)(ws + 2 * WT);
    unsigned short* hbuf = xbf + (size_t)chunk * D_;
    for (long r0 = 0; r0 < total_rows; r0 += chunk) {
      long nr = total_rows - r0;
      if (nr > chunk) nr = chunk;
      cvt_bf16_kernel<<<512, 256, 0, stream>>>(x + r0 * D_, xbf, nr * D_ / 4);
      int nbm = (int)(nr / 256);
      g1<<<dim3(nbm * (F_ / 256)), 512, 131072, stream>>>(
          xbf, w1t, b1, eidx, ew, hbuf, (int)r0, nbm);
      g2<<<dim3(nbm * (D_ / 256)), 512, 131072, stream>>>(
          hbuf, w2t, b2, eidx, ew, out + r0 * D_, (int)r0, nbm);
    }
  }
}

// Round 8
// 698.113 us; speedup vs baseline: 1.6560x; 1.1810x over previous
//
#include <hip/hip_runtime.h>
#include <hip/hip_bf16.h>

// MoE expert MLP: y[b] = (gelu(x[b] @ W1[e] + b1[e]) @ W2[e] + b2[e]) * w[b]
// B=8, S=4096, D=1024, F=4096, E=8. f32 in/out; bf16 MFMA 16x16x32, 256^2 tile.
// R8 = R5 inner loop (best measured) + coalesced g1 epilogue + L3-chunked H.

#define B_ 8
#define S_ 4096
#define D_ 1024
#define F_ 4096
#define E_ 8

typedef __bf16 bf16x8 __attribute__((ext_vector_type(8)));
typedef float f32x4 __attribute__((ext_vector_type(4)));

__device__ __forceinline__ unsigned short f2bf(float f) {
  unsigned u = __float_as_uint(f);
  u += 0x7FFFu + ((u >> 16) & 1u);   // round-to-nearest-even
  return (unsigned short)(u >> 16);
}

#define GLD16(g, l) __builtin_amdgcn_global_load_lds(                         \
    (const __attribute__((address_space(1))) unsigned int*)(g),              \
    (__attribute__((address_space(3))) unsigned int*)(l), 16, 0, 0)

// ---------------------------------------------------------------------------
// Transpose + f32->bf16:  src (nmat, R, C) f32  ->  dst (nmat, C, R) bf16
// ---------------------------------------------------------------------------
__global__ __launch_bounds__(256) void transpose_cvt_kernel(
    const float* __restrict__ src, unsigned short* __restrict__ dst,
    int R, int C) {
  __shared__ float t[32][33];
  const float* s = src + (size_t)blockIdx.z * R * C;
  unsigned short* d = dst + (size_t)blockIdx.z * R * C;
  int c0 = blockIdx.x * 32, r0 = blockIdx.y * 32;
  int x = threadIdx.x, y = threadIdx.y;      // 32 x 8
#pragma unroll
  for (int j = 0; j < 32; j += 8)
    t[y + j][x] = s[(size_t)(r0 + y + j) * C + (c0 + x)];
  __syncthreads();
#pragma unroll
  for (int j = 0; j < 32; j += 8)
    d[(size_t)(c0 + y + j) * R + (r0 + x)] = f2bf(t[x][y + j]);
}

// ---------------------------------------------------------------------------
// f32 -> bf16 flat convert, vectorized
// ---------------------------------------------------------------------------
__global__ __launch_bounds__(256) void cvt_bf16_kernel(
    const float* __restrict__ src, unsigned short* __restrict__ dst, long n4) {
  long i = (long)blockIdx.x * 256 + threadIdx.x;
  long stride = (long)gridDim.x * 256;
  for (; i < n4; i += stride) {
    float4 v = ((const float4*)src)[i];
    uint2 o;
    o.x = (unsigned)f2bf(v.x) | ((unsigned)f2bf(v.y) << 16);
    o.y = (unsigned)f2bf(v.z) | ((unsigned)f2bf(v.w) << 16);
    ((uint2*)dst)[i] = o;
  }
}

// ---------------------------------------------------------------------------
// 256x256-tile 4-phase GEMM (R5 schedule, best measured).
//   8 waves (2M x 4N), per-wave 128x64 output, BK=64, mfma 16x16x32 bf16.
//   LDS 128 KiB: buf{0,1} x { A[2 halves 128x64] , B[2 halves 128x64] },
//   16B-chunk XOR swizzle: chunk cc of row r holds global k-chunk cc^(r&7).
//   Staging issue order per tile t: ph1 Ah1(t+1), ph2 Ah0(t+2), ph3 Bh0(t+2),
//   ph4 Bh1(t+2); vmcnt(6) only at ph4 (3 half-tiles in flight).
//   R8 adds: GELU epilogue routes C-tile through LDS (K-loop smem is dead by
//   then) and writes 512B-contiguous row segments -> no partial-line RMW.
// ---------------------------------------------------------------------------

#define STAGE(cur, op, h, tk, base)                                           \
  {                                                                           \
    const unsigned short* g0_ = (base) + (size_t)((h) * 128 + sr) * LDK +     \
                                (tk) * 64 + sgc * 8;                          \
    GLD16(g0_, smem + (cur) * 65536 + (op) * 32768 + (h) * 16384 +            \
                   wave * 1024);                                              \
    GLD16(g0_ + (size_t)64 * LDK,                                             \
          smem + (cur) * 65536 + (op) * 32768 + (h) * 16384 + 8192 +          \
              wave * 1024);                                                   \
  }

#define LDA_HALF(cur, H)                                                      \
  _Pragma("unroll") for (int m = 0; m < 4; ++m) {                             \
    const char* p_ = smem + (cur) * 65536 + (H) * 16384 +                     \
                     (wr * 64 + m * 16 + l15) * 128;                          \
    aM[m][0] = *(const bf16x8*)(p_ + ca0);                                    \
    aM[m][1] = *(const bf16x8*)(p_ + ca1);                                    \
  }

#define LDB_Q(cur, Q, breg)                                                   \
  _Pragma("unroll") for (int n = 0; n < 2; ++n) {                             \
    const char* p_ = smem + (cur) * 65536 + 32768 + (Q) * 16384 +             \
                     (wc * 32 + n * 16 + l15) * 128;                          \
    breg[n][0] = *(const bf16x8*)(p_ + ca0);                                  \
    breg[n][1] = *(const bf16x8*)(p_ + ca1);                                  \
  }

#define MMA_Q(MB, breg, NB)                                                   \
  _Pragma("unroll") for (int ks = 0; ks < 2; ++ks)                            \
      _Pragma("unroll") for (int m = 0; m < 4; ++m)                           \
          _Pragma("unroll") for (int n = 0; n < 2; ++n)                       \
              acc[(MB) + m][(NB) + n] =                                       \
      __builtin_amdgcn_mfma_f32_16x16x32_bf16(                                \
          aM[m][ks], breg[n][ks], acc[(MB) + m][(NB) + n], 0, 0, 0);

#define PH_END                                                                \
  __builtin_amdgcn_s_setprio(0);                                              \
  __builtin_amdgcn_sched_barrier(0);                                          \
  __builtin_amdgcn_s_barrier();

// MODE: 2 = full staging, 1 = tail-1 (stage Ah1 only, drain), 0 = last tile
#define TILE(cur, t, MODE)                                                    \
  LDA_HALF(cur, 0);                                                           \
  LDB_Q(cur, 0, bq0);                                                         \
  if ((MODE) >= 1) STAGE((cur) ^ 1, 0, 1, (t) + 1, Abase);                    \
  __builtin_amdgcn_s_setprio(1);                                              \
  MMA_Q(0, bq0, 0);                                                           \
  PH_END;                                                                     \
  LDB_Q(cur, 1, bq1);                                                         \
  if ((MODE) == 2) STAGE(cur, 0, 0, (t) + 2, Abase);                          \
  __builtin_amdgcn_s_setprio(1);                                              \
  MMA_Q(0, bq1, 2);                                                           \
  PH_END;                                                                     \
  LDA_HALF(cur, 1);                                                           \
  if ((MODE) == 2) STAGE(cur, 1, 0, (t) + 2, Bbase);                          \
  __builtin_amdgcn_s_setprio(1);                                              \
  MMA_Q(4, bq0, 0);                                                           \
  PH_END;                                                                     \
  if ((MODE) == 2) STAGE(cur, 1, 1, (t) + 2, Bbase);                          \
  __builtin_amdgcn_s_setprio(1);                                              \
  MMA_Q(4, bq1, 2);                                                           \
  __builtin_amdgcn_s_setprio(0);                                              \
  __builtin_amdgcn_sched_barrier(0);                                          \
  if ((MODE) == 2) asm volatile("s_waitcnt vmcnt(6)" ::: "memory");           \
  if ((MODE) == 1) asm volatile("s_waitcnt vmcnt(0)" ::: "memory");           \
  __builtin_amdgcn_s_barrier();

template <int NT, int LDK, int NCOL, bool GELU>
__global__ __launch_bounds__(512, 2) void gemm8p_kernel(
    const unsigned short* __restrict__ A,   // [rows][LDK] bf16 (chunk-local)
    const unsigned short* __restrict__ Bw,  // [E][NCOL][LDK] bf16
    const float* __restrict__ bias,         // [E][NCOL]
    const int* __restrict__ eidx, const float* __restrict__ ew,
    void* __restrict__ Out, int grow0, int nbm) {
  extern __shared__ __align__(16) char smem[];

  const int tid = threadIdx.x;
  const int lane = tid & 63;
  const int wave = tid >> 6;
  const int wr = wave >> 2;         // 0..1 (M)
  const int wc = wave & 3;          // 0..3 (N)
  const int l15 = lane & 15, lhi = lane >> 4;

  const int nwg = nbm * (NCOL / 256);
  int wg = blockIdx.x;
  if ((nwg & 7) == 0) wg = (wg & 7) * (nwg >> 3) + (wg >> 3);  // XCD swizzle
  const int bm = wg % nbm, bn = wg / nbm;

  const int bat = (grow0 + bm * 256) >> 12;
  const int e = eidx[bat];

  const unsigned short* Abase = A + (size_t)bm * 256 * LDK;
  const unsigned short* Bbase =
      Bw + (size_t)e * (F_ * D_) + (size_t)bn * 256 * LDK;

  // staging per-thread constants (swizzled source)
  const int sr = tid >> 3;                  // 0..63 (row within 64-row slab)
  const int sgc = (tid & 7) ^ (sr & 7);     // global 16B chunk for lds chunk
  // ds_read per-thread swizzled chunk offsets (row&7 == l15&7 always)
  const int ca0 = ((lhi ^ (l15 & 7)) << 4);
  const int ca1 = (((4 + lhi) ^ (l15 & 7)) << 4);

  f32x4 acc[8][4] = {};
  bf16x8 aM[4][2], bq0[2][2], bq1[2][2];

  // prologue: tile0 all 4 halves, tile1 first 3 (Ah0,Bh0,Bh1)
  STAGE(0, 0, 0, 0, Abase);
  STAGE(0, 1, 0, 0, Bbase);
  STAGE(0, 1, 1, 0, Bbase);
  STAGE(0, 0, 1, 0, Abase);
  STAGE(1, 0, 0, 1, Abase);
  STAGE(1, 1, 0, 1, Bbase);
  STAGE(1, 1, 1, 1, Bbase);
  asm volatile("s_waitcnt vmcnt(6)" ::: "memory");
  __builtin_amdgcn_s_barrier();

#pragma unroll 1
  for (int t = 0; t < NT - 2; t += 2) {
    TILE(0, t, 2);
    TILE(1, t + 1, 2);
  }
  TILE(0, NT - 2, 1);
  TILE(1, NT - 1, 0);

  if (GELU) {
    // --- coalesced bf16 epilogue through LDS ---
    // Last tile (MODE 0) has no trailing barrier; other waves may still have
    // ds_reads outstanding on smem -> barrier before overwriting.
    __builtin_amdgcn_s_barrier();
    unsigned short* cs = (unsigned short*)smem;  // C-tile [256][256] bf16
#pragma unroll
    for (int n = 0; n < 4; ++n) {
      const int tcol =
          (n < 2 ? wc * 32 + n * 16 : 128 + wc * 32 + (n - 2) * 16) + l15;
      const float bv = bias[(size_t)e * NCOL + bn * 256 + tcol];
#pragma unroll
      for (int m = 0; m < 8; ++m) {
        const int trow =
            (m < 4 ? wr * 64 + m * 16 : 128 + wr * 64 + (m - 4) * 16) +
            lhi * 4;
#pragma unroll
        for (int r = 0; r < 4; ++r) {
          float v = acc[m][n][r] + bv;
          // tanh-form gelu: v * sigmoid(2 * 0.79788456*(v + 0.044715 v^3))
          float zz = v * (0.79788456080286536f + 0.0356774081f * v * v);
          float g = v / (1.0f + __expf(-2.0f * zz));
          cs[(trow + r) * 256 + tcol] = f2bf(g);
        }
      }
    }
    __builtin_amdgcn_s_barrier();
    unsigned short* Hо = (unsigned short*)Out + (size_t)bm * 256 * NCOL +
                         (size_t)bn * 256;
    const int rsub = tid >> 5, cc = tid & 31;
#pragma unroll
    for (int it = 0; it < 16; ++it) {
      const int row = it * 16 + rsub;
      *(uint4*)(Hо + (size_t)row * NCOL + cc * 8) =
          *(const uint4*)(smem + row * 512 + cc * 16);
    }
  } else {
    // f32 output: 16 lanes x 4B = 64B contiguous, sector-coalesced already
    const float scale = ew[bat];
#pragma unroll
    for (int n = 0; n < 4; ++n) {
      const int tcol =
          (n < 2 ? wc * 32 + n * 16 : 128 + wc * 32 + (n - 2) * 16) + l15;
      const int col = bn * 256 + tcol;
      const float bv = bias[(size_t)e * NCOL + col];
#pragma unroll
      for (int m = 0; m < 8; ++m) {
        const int trow =
            (m < 4 ? wr * 64 + m * 16 : 128 + wr * 64 + (m - 4) * 16) +
            lhi * 4;
        const size_t rowb = (size_t)bm * 256 + trow;
#pragma unroll
        for (int r = 0; r < 4; ++r)
          ((float*)Out)[(rowb + r) * NCOL + col] = (acc[m][n][r] + bv) * scale;
      }
    }
  }
}

// ---------------------------------------------------------------------------
extern "C" void kernel_launch(void* const* d_in, const int* in_sizes, int n_in,
                              void* d_out, int out_size, void* d_ws,
                              size_t ws_size, hipStream_t stream) {
  const float* x = (const float*)d_in[0];
  const float* ew = (const float*)d_in[1];
  const float* W1 = (const float*)d_in[2];
  const float* b1 = (const float*)d_in[3];
  const float* W2 = (const float*)d_in[4];
  const float* b2 = (const float*)d_in[5];
  const int* eidx = (const int*)d_in[6];
  float* out = (float*)d_out;

  char* ws = (char*)d_ws;
  const size_t WT = (size_t)E_ * F_ * D_ * 2;  // 64 MiB per transposed weight
  const size_t XB = (size_t)B_ * S_ * D_ * 2;  // 64 MiB bf16 x
  unsigned short* w1t = (unsigned short*)ws;
  unsigned short* w2t = (unsigned short*)(ws + WT);

  auto g1 = gemm8p_kernel<16, D_, F_, true>;
  auto g2 = gemm8p_kernel<64, F_, D_, false>;
  hipFuncSetAttribute((const void*)g1,
                      hipFuncAttributeMaxDynamicSharedMemorySize, 131072);
  hipFuncSetAttribute((const void*)g2,
                      hipFuncAttributeMaxDynamicSharedMemorySize, 131072);

  // weights: W1 (E,D,F)->(E,F,D), W2 (E,F,D)->(E,D,F), bf16
  transpose_cvt_kernel<<<dim3(F_ / 32, D_ / 32, E_), dim3(32, 8), 0, stream>>>(
      W1, w1t, D_, F_);
  transpose_cvt_kernel<<<dim3(D_ / 32, F_ / 32, E_), dim3(32, 8), 0, stream>>>(
      W2, w2t, F_, D_);

  const long total_rows = (long)B_ * S_;  // 32768

  // Preferred: full xbf + hbuf chunked at <=16384 rows so H stays L3-resident
  // (H-chunk 128 MB, reused across chunks). g2 grid stays >= 1 block/CU.
  long avail = (long)ws_size - (long)(2 * WT + XB);
  long CH = avail > 0 ? (avail / ((long)F_ * 2)) : 0;
  CH = (CH / 256) * 256;
  if (CH > 16384) CH = 16384;
  if (CH > total_rows) CH = total_rows;

  if (CH >= 256) {
    unsigned short* xbf = (unsigned short*)(ws + 2 * WT);
    unsigned short* hbuf = (unsigned short*)(ws + 2 * WT + XB);
    cvt_bf16_kernel<<<2048, 256, 0, stream>>>(x, xbf, (long)B_ * S_ * D_ / 4);
    for (long r0 = 0; r0 < total_rows; r0 += CH) {
      long nr = total_rows - r0;
      if (nr > CH) nr = CH;
      int nbm = (int)(nr / 256);
      g1<<<dim3(nbm * (F_ / 256)), 512, 131072, stream>>>(
          xbf + r0 * D_, w1t, b1, eidx, ew, hbuf, (int)r0, nbm);
      g2<<<dim3(nbm * (D_ / 256)), 512, 131072, stream>>>(
          hbuf, w2t, b2, eidx, ew, out + r0 * D_, (int)r0, nbm);
    }
  } else {
    // tiny-ws fallback: chunk xbf and hbuf together
    long cap = ((long)ws_size - (long)(2 * WT)) / ((long)(D_ + F_) * 2);
    long chunk = (cap / 256) * 256;
    if (chunk > total_rows) chunk = total_rows;
    if (chunk < 256) chunk = 256;
    unsigned short* xbf = (unsigned short*)(ws + 2 * WT);
    unsigned short* hbuf = xbf + (size_t)chunk * D_;
    for (long r0 = 0; r0 < total_rows; r0 += chunk) {
      long nr = total_rows - r0;
      if (nr > chunk) nr = chunk;
      cvt_bf16_kernel<<<512, 256, 0, stream>>>(x + r0 * D_, xbf, nr * D_ / 4);
      int nbm = (int)(nr / 256);
      g1<<<dim3(nbm * (F_ / 256)), 512, 131072, stream>>>(
          xbf, w1t, b1, eidx, ew, hbuf, (int)r0, nbm);
      g2<<<dim3(nbm * (D_ / 256)), 512, 131072, stream>>>(
          hbuf, w2t, b2, eidx, ew, out + r0 * D_, (int)r0, nbm);
    }
  }
}